// Round 1
// baseline (96.792 us; speedup 1.0000x reference)
//
#include <hip/hip_runtime.h>
#include <hip/hip_bf16.h>

// Problem geometry (fixed by the reference)
constexpr int HH = 4096;          // image height
constexpr int WW = 4096;          // image width
constexpr int BXB = 1024;         // 4x4 blocks per image row (W/4)
constexpr int NB  = 1048576;      // total 4x4 blocks (BY*BX)

__device__ __forceinline__ float sigmoidf_fast(float x) {
    // 1/(1+e^-x); __expf -> v_exp_f32, plenty accurate for 0.19 absmax budget
    return 1.0f / (1.0f + __expf(-x));
}

__global__ __launch_bounds__(256) void bc6_decode_kernel(
    const float* __restrict__ endpoints,   // (NB,4,3)
    const float* __restrict__ indices,     // (NB,16)
    const float* __restrict__ logits,      // (NB,32)
    const float* __restrict__ bank,        // (32,16) 0/1
    const float* __restrict__ lut,         // (8,)
    float* __restrict__ out)               // (3,H,W)
{
    // Stage the tiny shared tables in LDS.
    // s_bank rows as float4 so the matvec uses ds_read_b128 (uniform addr -> broadcast).
    __shared__ float4 s_bank[32][4];
    __shared__ float  s_lut[8];

    const int tid = threadIdx.x;
    if (tid < 128) {
        reinterpret_cast<float4*>(s_bank)[tid] =
            reinterpret_cast<const float4*>(bank)[tid];
    }
    if (tid < 8) s_lut[tid] = lut[tid];
    __syncthreads();

    const int b = blockIdx.x * 256 + tid;   // one thread per BC block

    // ---------------- logits -> softmax numerators (in place) ----------------
    float lv[32];
    {
        const float4* p = reinterpret_cast<const float4*>(logits) + (size_t)b * 8;
        #pragma unroll
        for (int q = 0; q < 8; ++q) {
            float4 v = p[q];
            lv[q*4+0] = v.x; lv[q*4+1] = v.y; lv[q*4+2] = v.z; lv[q*4+3] = v.w;
        }
    }
    float mmax = lv[0];
    #pragma unroll
    for (int k = 1; k < 32; ++k) mmax = fmaxf(mmax, lv[k]);
    float esum = 0.0f;
    #pragma unroll
    for (int k = 0; k < 32; ++k) { lv[k] = __expf(lv[k] - mmax); esum += lv[k]; }
    const float inv_sum = 1.0f / esum;

    // ---------------- mask = softmax(p) @ bank  (32x16 matvec) ----------------
    float maskv[16];
    #pragma unroll
    for (int j = 0; j < 16; ++j) maskv[j] = 0.0f;
    #pragma unroll
    for (int k = 0; k < 32; ++k) {
        const float ek = lv[k];
        #pragma unroll
        for (int q = 0; q < 4; ++q) {
            const float4 r = s_bank[k][q];   // ds_read_b128, broadcast
            maskv[q*4+0] = fmaf(ek, r.x, maskv[q*4+0]);
            maskv[q*4+1] = fmaf(ek, r.y, maskv[q*4+1]);
            maskv[q*4+2] = fmaf(ek, r.z, maskv[q*4+2]);
            maskv[q*4+3] = fmaf(ek, r.w, maskv[q*4+3]);
        }
    }
    #pragma unroll
    for (int j = 0; j < 16; ++j) maskv[j] *= inv_sum;

    // ---------------- endpoints -> e_u (12 values) ----------------
    float eu[12];
    {
        const float4* p = reinterpret_cast<const float4*>(endpoints) + (size_t)b * 3;
        #pragma unroll
        for (int q = 0; q < 3; ++q) {
            const float4 v = p[q];
            const float t4[4] = { v.x, v.y, v.z, v.w };
            #pragma unroll
            for (int t = 0; t < 4; ++t) {
                const float eq = sigmoidf_fast(t4[t]) * 63.0f;
                const float e1 = (eq * 65536.0f + 32768.0f) * (1.0f / 64.0f);
                eu[q*4 + t] = e1 * (31.0f / 64.0f);
            }
        }
    }

    // ---------------- indices -> per-pixel weights (16 values) ----------------
    float wv[16];
    {
        const float4* p = reinterpret_cast<const float4*>(indices) + (size_t)b * 4;
        #pragma unroll
        for (int q = 0; q < 4; ++q) {
            const float4 v = p[q];
            const float t4[4] = { v.x, v.y, v.z, v.w };
            #pragma unroll
            for (int t = 0; t < 4; ++t) {
                const float xn = sigmoidf_fast(t4[t]);
                const float xs = xn * 7.0f;
                const float x0f = floorf(xs);
                int x0 = (int)x0f;
                x0 = x0 < 0 ? 0 : (x0 > 7 ? 7 : x0);
                const int x1 = (x0 + 1 > 7) ? 7 : (x0 + 1);
                float frac = xs - x0f;
                frac = fminf(fmaxf(frac, 0.0f), 1.0f);
                const float w0 = s_lut[x0];   // 8-word table: broadcast, no conflicts
                const float w1 = s_lut[x1];
                wv[q*4 + t] = w0 * (1.0f - frac) + w1 * frac;
            }
        }
    }

    // ---------------- decode + store ----------------
    // img[c, by*4+py, bx*4+px] = blocks[b, py*4+px, c]
    const int by = b >> 10;           // b / BXB
    const int bx = b & (BXB - 1);     // b % BXB

    #pragma unroll
    for (int c = 0; c < 3; ++c) {
        const float euA = eu[0 + c];   // endpoint 0
        const float euB = eu[3 + c];   // endpoint 1
        const float euC = eu[6 + c];   // endpoint 2
        const float euD = eu[9 + c];   // endpoint 3
        #pragma unroll
        for (int py = 0; py < 4; ++py) {
            float o4[4];
            #pragma unroll
            for (int px = 0; px < 4; ++px) {
                const int j = py * 4 + px;
                const float wj = wv[j];
                const float y1 = euA * (1.0f - wj) + euB * wj;
                const float y2 = euC * (1.0f - wj) + euD * wj;
                const float mj = maskv[j];
                const float y  = mj * y1 + (1.0f - mj) * y2;
                float hh = floorf((y - 1.0f) * (1.0f / 1024.0f)) - 1.0f;
                hh = fminf(fmaxf(hh, 0.0f), 31.0f);
                o4[px] = exp2f(hh - 14.0f) * (y * (1.0f / 1024.0f) - hh);
            }
            float4* dst = reinterpret_cast<float4*>(
                out + (size_t)c * HH * WW + (size_t)(by * 4 + py) * WW) + bx;
            *dst = make_float4(o4[0], o4[1], o4[2], o4[3]);
        }
    }
}

extern "C" void kernel_launch(void* const* d_in, const int* in_sizes, int n_in,
                              void* d_out, int out_size, void* d_ws, size_t ws_size,
                              hipStream_t stream) {
    const float* endpoints = (const float*)d_in[0];
    const float* indices   = (const float*)d_in[1];
    const float* logits    = (const float*)d_in[2];
    const float* bank      = (const float*)d_in[3];
    const float* lut       = (const float*)d_in[4];
    float* out             = (float*)d_out;

    const int threads = 256;
    const int blocks  = NB / threads;   // 4096
    bc6_decode_kernel<<<blocks, threads, 0, stream>>>(
        endpoints, indices, logits, bank, lut, out);
}